// Round 3
// baseline (677.942 us; speedup 1.0000x reference)
//
#include <hip/hip_runtime.h>
#include <math.h>

#define D 128

typedef unsigned int u32;

__device__ __forceinline__ u32 rotl32(u32 x, int r){ return (x<<r) | (x>>(32-r)); }

// eps = jax.random.normal(jax.random.key(42), ...), element m (row-major flat).
// JAX threefry PARTITIONABLE layout (default in modern JAX): each element has a
// 64-bit counter (hi, lo) = (0, m) for m < 2^32; key = (0, 42);
// 32-bit output = x0_final ^ x1_final  (XOR of both threefry output words).
// Then uniform in [-1+2^-24, 1) and sqrt(2)*erfinv (XLA Giles polynomial).
__device__ __forceinline__ float jax_normal_part_xor(u32 m){
  const u32 ks0 = 0u, ks1 = 42u, ks2 = 0x1BD11BF0u; // 0x1BD11BDA ^ 0 ^ 42
  u32 x0 = 0u + ks0;   // counts_hi + ks0
  u32 x1 = m  + ks1;   // counts_lo + ks1
  #define TF_R4(a,b,c,d) \
    x0 += x1; x1 = rotl32(x1,(a)); x1 ^= x0; \
    x0 += x1; x1 = rotl32(x1,(b)); x1 ^= x0; \
    x0 += x1; x1 = rotl32(x1,(c)); x1 ^= x0; \
    x0 += x1; x1 = rotl32(x1,(d)); x1 ^= x0;
  TF_R4(13,15,26,6)   x0 += ks1; x1 += ks2 + 1u;
  TF_R4(17,29,16,24)  x0 += ks2; x1 += ks0 + 2u;
  TF_R4(13,15,26,6)   x0 += ks0; x1 += ks1 + 3u;
  TF_R4(17,29,16,24)  x0 += ks1; x1 += ks2 + 4u;
  TF_R4(13,15,26,6)   x0 += ks2; x1 += ks0 + 5u;
  #undef TF_R4
  u32 bits = x0 ^ x1;
  float f = __uint_as_float((bits >> 9) | 0x3F800000u) - 1.0f;   // [0,1)
  const float LO = -0.99999994f;                                  // nextafter(-1,0)
  // (hi - lo) rounds to exactly 2.0f in f32
  float u = fmaxf(LO, f * 2.0f + LO);
  float w = -log1pf(-u*u);
  float p;
  if (w < 5.0f){
    w -= 2.5f;
    p =  2.81022636e-08f;
    p = fmaf(p, w,  3.43273939e-07f);
    p = fmaf(p, w, -3.5233877e-06f);
    p = fmaf(p, w, -4.39150654e-06f);
    p = fmaf(p, w,  0.00021858087f);
    p = fmaf(p, w, -0.00125372503f);
    p = fmaf(p, w, -0.00417768164f);
    p = fmaf(p, w,  0.246640727f);
    p = fmaf(p, w,  1.50140941f);
  } else {
    w = sqrtf(w) - 3.0f;
    p = -0.000200214257f;
    p = fmaf(p, w,  0.000100950558f);
    p = fmaf(p, w,  0.00134934322f);
    p = fmaf(p, w, -0.00367342844f);
    p = fmaf(p, w,  0.00573950773f);
    p = fmaf(p, w, -0.0076224613f);
    p = fmaf(p, w,  0.00943887047f);
    p = fmaf(p, w,  1.00167406f);
    p = fmaf(p, w,  2.83297682f);
  }
  return 1.41421354f * (p * u);
}

__device__ __forceinline__ float sigmoidf_(float z){ return 1.0f / (1.0f + expf(-z)); }

// ---------------- index normalization (int32 vs int64 edge_index) ----------------
__global__ void k_detect(const u32* __restrict__ e_u32, int* __restrict__ flag){
  __shared__ int s_nz;
  if (threadIdx.x == 0) s_nz = 0;
  __syncthreads();
  if (e_u32[2*threadIdx.x + 1] != 0u) atomicAdd(&s_nz, 1);
  __syncthreads();
  if (threadIdx.x == 0) *flag = (s_nz == 0) ? 1 : 0;   // all-hi-words-zero => int64
}

__global__ void k_norm(const void* __restrict__ eidx, const int* __restrict__ flag,
                       int* __restrict__ src_w, int* __restrict__ dst_w, int e){
  int i = blockIdx.x*256 + threadIdx.x;
  if (i >= e) return;
  if (*flag){
    const u32* u = (const u32*)eidx;
    src_w[i] = (int)u[2*(size_t)i];
    dst_w[i] = (int)u[2*((size_t)e + i)];
  } else {
    const int* p = (const int*)eidx;
    src_w[i] = p[i];
    dst_w[i] = p[e + i];
  }
}

// ---------------- degree / CSR build ----------------
__global__ void k_init(int* __restrict__ cnt, float* __restrict__ degsc,
                       double* __restrict__ klacc, int n){
  int i = blockIdx.x*256 + threadIdx.x;
  if (i < n){ cnt[i] = 0; degsc[i] = 1.0f; }  // 1.0 = self-loop weight
  if (i == 0) *klacc = 0.0;
}

__global__ void k_hist(const int* __restrict__ dst, const float* __restrict__ sc,
                       int* __restrict__ cnt, float* __restrict__ degsc, int e){
  int i = blockIdx.x*256 + threadIdx.x;
  if (i >= e) return;
  int d = dst[i];
  atomicAdd(&cnt[d], 1);
  atomicAdd(&degsc[d], sc[i]);
}

__global__ __launch_bounds__(256) void k_scan1(const int* __restrict__ cnt,
                                               int* __restrict__ rp,
                                               int* __restrict__ bsum, int n){
  __shared__ int sh[256];
  int tid = threadIdx.x, idx = blockIdx.x*256 + tid;
  int v = (idx < n) ? cnt[idx] : 0;
  sh[tid] = v; __syncthreads();
  for (int off = 1; off < 256; off <<= 1){
    int t = (tid >= off) ? sh[tid-off] : 0;
    __syncthreads(); sh[tid] += t; __syncthreads();
  }
  if (idx < n) rp[idx] = sh[tid] - v;     // exclusive within chunk
  if (tid == 255) bsum[blockIdx.x] = sh[255];
}

__global__ __launch_bounds__(1024) void k_scan2(int* __restrict__ bsum, int nb){
  __shared__ int sh[1024];
  int tid = threadIdx.x;
  int v = (tid < nb) ? bsum[tid] : 0;
  sh[tid] = v; __syncthreads();
  for (int off = 1; off < 1024; off <<= 1){
    int t = (tid >= off) ? sh[tid-off] : 0;
    __syncthreads(); sh[tid] += t; __syncthreads();
  }
  if (tid < nb) bsum[tid] = sh[tid] - v;  // exclusive block offsets
}

__global__ void k_scan3(int* __restrict__ rp, int* __restrict__ cur,
                        const int* __restrict__ bsum, const int* __restrict__ cnt,
                        const float* __restrict__ degsc,
                        float* __restrict__ dinv_s, float* __restrict__ dinv_o,
                        int n, int e){
  int idx = blockIdx.x*256 + threadIdx.x;
  if (idx < n){
    int r = rp[idx] + bsum[blockIdx.x];
    rp[idx] = r; cur[idx] = r;
    dinv_o[idx] = rsqrtf((float)(cnt[idx] + 1));
    dinv_s[idx] = rsqrtf(degsc[idx]);
  }
  if (idx == 0) rp[n] = e;
}

__global__ void k_scatter(const int* __restrict__ src, const int* __restrict__ dst,
                          const float* __restrict__ sc, int* __restrict__ cur,
                          int* __restrict__ col, float* __restrict__ wsrt, int e){
  int i = blockIdx.x*256 + threadIdx.x;
  if (i >= e) return;
  int d = dst[i];
  int p = atomicAdd(&cur[d], 1);
  col[p] = src[i];
  wsrt[p] = sc[i];
}

// ---------------- aggregations: one wave per node, lane holds 2 of 128 dims ----------------
__global__ __launch_bounds__(256) void k_agg_dual(
    const float* __restrict__ x, const int* __restrict__ rp,
    const int* __restrict__ col, const float* __restrict__ wsrt,
    const float* __restrict__ dinv_s, const float* __restrict__ dinv_o,
    float* __restrict__ out_s, float* __restrict__ out_o, int n){
  int wid = (blockIdx.x * 256 + threadIdx.x) >> 6;
  int lane = threadIdx.x & 63;
  if (wid >= n) return;
  const float2* x2 = (const float2*)x;
  float dsv = dinv_s[wid], dov = dinv_o[wid];
  float2 xv = x2[(size_t)wid*64 + lane];
  float ss = dsv*dsv, oo = dov*dov;                      // self-loop (w=1)
  float2 as = { xv.x*ss, xv.y*ss };
  float2 ao = { xv.x*oo, xv.y*oo };
  int e0 = rp[wid], e1 = rp[wid+1];
  for (int i = e0; i < e1; ++i){
    int s = col[i];
    float ns = dinv_s[s] * wsrt[i] * dsv;
    float no = dinv_o[s] * dov;
    float2 xs = x2[(size_t)s*64 + lane];
    as.x = fmaf(ns, xs.x, as.x); as.y = fmaf(ns, xs.y, as.y);
    ao.x = fmaf(no, xs.x, ao.x); ao.y = fmaf(no, xs.y, ao.y);
  }
  ((float2*)out_s)[(size_t)wid*64 + lane] = as;
  ((float2*)out_o)[(size_t)wid*64 + lane] = ao;
}

__global__ __launch_bounds__(256) void k_agg_one(
    const float* __restrict__ h, const int* __restrict__ rp,
    const int* __restrict__ col, const float* __restrict__ dinv_o,
    float* __restrict__ out, int n){
  int wid = (blockIdx.x * 256 + threadIdx.x) >> 6;
  int lane = threadIdx.x & 63;
  if (wid >= n) return;
  const float2* h2 = (const float2*)h;
  float dov = dinv_o[wid];
  float2 hv = h2[(size_t)wid*64 + lane];
  float oo = dov*dov;
  float2 ao = { hv.x*oo, hv.y*oo };
  int e0 = rp[wid], e1 = rp[wid+1];
  for (int i = e0; i < e1; ++i){
    int s = col[i];
    float no = dinv_o[s] * dov;
    float2 hs = h2[(size_t)s*64 + lane];
    ao.x = fmaf(no, hs.x, ao.x); ao.y = fmaf(no, hs.y, ao.y);
  }
  ((float2*)out)[(size_t)wid*64 + lane] = ao;
}

// ---------------- GEMMs: 64-row tile, block=256, thread = 8 rows x 4 cols ----------------
#define GEMM_PROLOGUE(Abuf)                                                   \
  __shared__ float As[64][128];                                               \
  const int tid = threadIdx.x;                                                \
  const int row0 = blockIdx.x * 64;                                           \
  _Pragma("unroll")                                                           \
  for (int i = tid; i < 64*32; i += 256){                                     \
    int r = i >> 5, c4 = (i & 31) << 2;                                       \
    float4 v = {0.f,0.f,0.f,0.f};                                             \
    if (row0 + r < n) v = *(const float4*)((Abuf) + (size_t)(row0+r)*D + c4); \
    *(float4*)&As[r][c4] = v;                                                 \
  }                                                                           \
  __syncthreads();                                                            \
  const int tx = tid & 31, ty = tid >> 5;

__global__ __launch_bounds__(256) void k_gemm_act(
    const float* __restrict__ A, const float* __restrict__ W,
    const float* __restrict__ b, const float* __restrict__ temb,
    const int* __restrict__ t_ptr, int use_temb,
    float* __restrict__ out, int n){
  GEMM_PROLOGUE(A)
  float acc[8][4] = {};
  const float4* __restrict__ Wv = (const float4*)W;
  for (int kk = 0; kk < 128; kk += 4){
    float4 w0 = Wv[(kk+0)*32 + tx];
    float4 w1 = Wv[(kk+1)*32 + tx];
    float4 w2 = Wv[(kk+2)*32 + tx];
    float4 w3 = Wv[(kk+3)*32 + tx];
    #pragma unroll
    for (int r = 0; r < 8; ++r){
      float4 a = *(const float4*)&As[ty*8+r][kk];
      acc[r][0] = fmaf(a.x,w0.x, fmaf(a.y,w1.x, fmaf(a.z,w2.x, fmaf(a.w,w3.x, acc[r][0]))));
      acc[r][1] = fmaf(a.x,w0.y, fmaf(a.y,w1.y, fmaf(a.z,w2.y, fmaf(a.w,w3.y, acc[r][1]))));
      acc[r][2] = fmaf(a.x,w0.z, fmaf(a.y,w1.z, fmaf(a.z,w2.z, fmaf(a.w,w3.z, acc[r][2]))));
      acc[r][3] = fmaf(a.x,w0.w, fmaf(a.y,w1.w, fmaf(a.z,w2.w, fmaf(a.w,w3.w, acc[r][3]))));
    }
  }
  float4 bb = ((const float4*)b)[tx];
  float4 tt = {0.f,0.f,0.f,0.f};
  if (use_temb){ int t = *t_ptr; tt = ((const float4*)temb)[t*32 + tx]; }
  #pragma unroll
  for (int r = 0; r < 8; ++r){
    int row = row0 + ty*8 + r;
    if (row < n){
      float4 o;
      o.x = fmaxf(acc[r][0] + bb.x, 0.f) + tt.x;
      o.y = fmaxf(acc[r][1] + bb.y, 0.f) + tt.y;
      o.z = fmaxf(acc[r][2] + bb.z, 0.f) + tt.z;
      o.w = fmaxf(acc[r][3] + bb.w, 0.f) + tt.w;
      *(float4*)(out + (size_t)row*D + tx*4) = o;
    }
  }
}

// out1 = A@W1 + b1 (linear, prior_mean); out2 = sigmoid(A@W2 + b2) (prior_std)
__global__ __launch_bounds__(256) void k_gemm_dual(
    const float* __restrict__ A,
    const float* __restrict__ W1, const float* __restrict__ b1,
    const float* __restrict__ W2, const float* __restrict__ b2,
    float* __restrict__ out1, float* __restrict__ out2, int n){
  GEMM_PROLOGUE(A)
  float acc1[8][4] = {}; float acc2[8][4] = {};
  const float4* __restrict__ W1v = (const float4*)W1;
  const float4* __restrict__ W2v = (const float4*)W2;
  for (int kk = 0; kk < 128; kk += 4){
    float4 p0 = W1v[(kk+0)*32 + tx], q0 = W2v[(kk+0)*32 + tx];
    float4 p1 = W1v[(kk+1)*32 + tx], q1 = W2v[(kk+1)*32 + tx];
    float4 p2 = W1v[(kk+2)*32 + tx], q2 = W2v[(kk+2)*32 + tx];
    float4 p3 = W1v[(kk+3)*32 + tx], q3 = W2v[(kk+3)*32 + tx];
    #pragma unroll
    for (int r = 0; r < 8; ++r){
      float4 a = *(const float4*)&As[ty*8+r][kk];
      acc1[r][0] = fmaf(a.x,p0.x, fmaf(a.y,p1.x, fmaf(a.z,p2.x, fmaf(a.w,p3.x, acc1[r][0]))));
      acc1[r][1] = fmaf(a.x,p0.y, fmaf(a.y,p1.y, fmaf(a.z,p2.y, fmaf(a.w,p3.y, acc1[r][1]))));
      acc1[r][2] = fmaf(a.x,p0.z, fmaf(a.y,p1.z, fmaf(a.z,p2.z, fmaf(a.w,p3.z, acc1[r][2]))));
      acc1[r][3] = fmaf(a.x,p0.w, fmaf(a.y,p1.w, fmaf(a.z,p2.w, fmaf(a.w,p3.w, acc1[r][3]))));
      acc2[r][0] = fmaf(a.x,q0.x, fmaf(a.y,q1.x, fmaf(a.z,q2.x, fmaf(a.w,q3.x, acc2[r][0]))));
      acc2[r][1] = fmaf(a.x,q0.y, fmaf(a.y,q1.y, fmaf(a.z,q2.y, fmaf(a.w,q3.y, acc2[r][1]))));
      acc2[r][2] = fmaf(a.x,q0.z, fmaf(a.y,q1.z, fmaf(a.z,q2.z, fmaf(a.w,q3.z, acc2[r][2]))));
      acc2[r][3] = fmaf(a.x,q0.w, fmaf(a.y,q1.w, fmaf(a.z,q2.w, fmaf(a.w,q3.w, acc2[r][3]))));
    }
  }
  float4 bb1 = ((const float4*)b1)[tx];
  float4 bb2 = ((const float4*)b2)[tx];
  #pragma unroll
  for (int r = 0; r < 8; ++r){
    int row = row0 + ty*8 + r;
    if (row < n){
      float4 o1, o2;
      o1.x = acc1[r][0] + bb1.x; o1.y = acc1[r][1] + bb1.y;
      o1.z = acc1[r][2] + bb1.z; o1.w = acc1[r][3] + bb1.w;
      o2.x = sigmoidf_(acc2[r][0] + bb2.x); o2.y = sigmoidf_(acc2[r][1] + bb2.y);
      o2.z = sigmoidf_(acc2[r][2] + bb2.z); o2.w = sigmoidf_(acc2[r][3] + bb2.w);
      *(float4*)(out1 + (size_t)row*D + tx*4) = o1;
      *(float4*)(out2 + (size_t)row*D + tx*4) = o2;
    }
  }
}

// em = A@Wmu + bmu ; es = sigmoid(A@Wstd + bstd); conf = eps*es + em; kl accumulation
__global__ __launch_bounds__(256) void k_gemm_final(
    const float* __restrict__ A,
    const float* __restrict__ Wmu, const float* __restrict__ bmu,
    const float* __restrict__ Wstd, const float* __restrict__ bstd,
    const float* __restrict__ pm, const float* __restrict__ ps,
    float* __restrict__ conf, double* __restrict__ klacc, int n){
  GEMM_PROLOGUE(A)
  float acc1[8][4] = {}; float acc2[8][4] = {};
  const float4* __restrict__ W1v = (const float4*)Wmu;
  const float4* __restrict__ W2v = (const float4*)Wstd;
  for (int kk = 0; kk < 128; kk += 4){
    float4 p0 = W1v[(kk+0)*32 + tx], q0 = W2v[(kk+0)*32 + tx];
    float4 p1 = W1v[(kk+1)*32 + tx], q1 = W2v[(kk+1)*32 + tx];
    float4 p2 = W1v[(kk+2)*32 + tx], q2 = W2v[(kk+2)*32 + tx];
    float4 p3 = W1v[(kk+3)*32 + tx], q3 = W2v[(kk+3)*32 + tx];
    #pragma unroll
    for (int r = 0; r < 8; ++r){
      float4 a = *(const float4*)&As[ty*8+r][kk];
      acc1[r][0] = fmaf(a.x,p0.x, fmaf(a.y,p1.x, fmaf(a.z,p2.x, fmaf(a.w,p3.x, acc1[r][0]))));
      acc1[r][1] = fmaf(a.x,p0.y, fmaf(a.y,p1.y, fmaf(a.z,p2.y, fmaf(a.w,p3.y, acc1[r][1]))));
      acc1[r][2] = fmaf(a.x,p0.z, fmaf(a.y,p1.z, fmaf(a.z,p2.z, fmaf(a.w,p3.z, acc1[r][2]))));
      acc1[r][3] = fmaf(a.x,p0.w, fmaf(a.y,p1.w, fmaf(a.z,p2.w, fmaf(a.w,p3.w, acc1[r][3]))));
      acc2[r][0] = fmaf(a.x,q0.x, fmaf(a.y,q1.x, fmaf(a.z,q2.x, fmaf(a.w,q3.x, acc2[r][0]))));
      acc2[r][1] = fmaf(a.x,q0.y, fmaf(a.y,q1.y, fmaf(a.z,q2.y, fmaf(a.w,q3.y, acc2[r][1]))));
      acc2[r][2] = fmaf(a.x,q0.z, fmaf(a.y,q1.z, fmaf(a.z,q2.z, fmaf(a.w,q3.z, acc2[r][2]))));
      acc2[r][3] = fmaf(a.x,q0.w, fmaf(a.y,q1.w, fmaf(a.z,q2.w, fmaf(a.w,q3.w, acc2[r][3]))));
    }
  }
  float4 bb1 = ((const float4*)bmu)[tx];
  float4 bb2 = ((const float4*)bstd)[tx];
  const float EPS = 1e-9f;
  float klsum = 0.f;
  #pragma unroll
  for (int r = 0; r < 8; ++r){
    int row = row0 + ty*8 + r;
    if (row < n){
      float4 pmv = *(const float4*)(pm + (size_t)row*D + tx*4);
      float4 psv = *(const float4*)(ps + (size_t)row*D + tx*4);
      float em[4], es[4], pmf[4] = {pmv.x,pmv.y,pmv.z,pmv.w}, psf[4] = {psv.x,psv.y,psv.z,psv.w};
      float bmu4[4] = {bb1.x,bb1.y,bb1.z,bb1.w}, bsd4[4] = {bb2.x,bb2.y,bb2.z,bb2.w};
      #pragma unroll
      for (int c = 0; c < 4; ++c){
        em[c] = acc1[r][c] + bmu4[c];
        es[c] = sigmoidf_(acc2[r][c] + bsd4[c]);
        u32 m = (u32)row*128u + (u32)(tx*4 + c);
        float eps = jax_normal_part_xor(m);
        conf[m] = fmaf(eps, es[c], em[c]);
        float es_e = es[c] + EPS, ps_e = psf[c] + EPS;
        float diff = em[c] - pmf[c];
        klsum += 2.0f*(logf(ps_e) - logf(es_e))
               + (es_e*es_e + diff*diff) / (ps_e*ps_e) - 1.0f;
      }
    }
  }
  // wave reduce, one atomic per wave
  #pragma unroll
  for (int off = 32; off > 0; off >>= 1) klsum += __shfl_down(klsum, off);
  if ((tid & 63) == 0) atomicAdd(klacc, (double)klsum);
}

__global__ void k_finish(const double* __restrict__ klacc, float* __restrict__ out0, int n){
  if (threadIdx.x == 0 && blockIdx.x == 0)
    out0[0] = (float)(0.5 * (*klacc) / (double)n);
}

// ---------------------------------------------------------------------------
extern "C" void kernel_launch(void* const* d_in, const int* in_sizes, int n_in,
                              void* d_out, int out_size, void* d_ws, size_t ws_size,
                              hipStream_t stream){
  const void*  eidx   = d_in[0];
  const float* x      = (const float*)d_in[1];
  const int*   t_ptr  = (const int*)d_in[2];
  const float* escore = (const float*)d_in[3];
  const float* W_enc = (const float*)d_in[6];  const float* b_enc = (const float*)d_in[7];
  const float* W_mu  = (const float*)d_in[8];  const float* b_mu  = (const float*)d_in[9];
  const float* W_std = (const float*)d_in[10]; const float* b_std = (const float*)d_in[11];
  const float* W_pr  = (const float*)d_in[12]; const float* b_pr  = (const float*)d_in[13];
  const float* W_pm  = (const float*)d_in[14]; const float* b_pm  = (const float*)d_in[15];
  const float* W_ps  = (const float*)d_in[16]; const float* b_ps  = (const float*)d_in[17];
  const float* temb  = (const float*)d_in[18];

  const int N = in_sizes[1] / D;
  const int E = in_sizes[3];

  char* w = (char*)d_ws;
  auto alloc = [&](size_t bytes) -> char* {
    char* p = w; w += (bytes + 255) & ~(size_t)255; return p;
  };
  int*    flag   = (int*)   alloc(256);
  int*    src_w  = (int*)   alloc((size_t)E*4);
  int*    dst_w  = (int*)   alloc((size_t)E*4);
  int*    cnt    = (int*)   alloc((size_t)N*4);
  int*    rp     = (int*)   alloc((size_t)(N+1)*4);
  int*    cur    = (int*)   alloc((size_t)N*4);
  float*  degsc  = (float*) alloc((size_t)N*4);
  float*  dinv_s = (float*) alloc((size_t)N*4);
  float*  dinv_o = (float*) alloc((size_t)N*4);
  int*    bsum   = (int*)   alloc(1024*4);
  double* klacc  = (double*)alloc(256);
  int*    col    = (int*)   alloc((size_t)E*4);
  float*  wsrt   = (float*) alloc((size_t)E*4);
  float*  B1     = (float*) alloc((size_t)N*D*4);  // agg_score_x -> prior
  float*  B2     = (float*) alloc((size_t)N*D*4);  // agg_ones_x  -> agg_ones_enc
  float*  B3     = (float*) alloc((size_t)N*D*4);  // enc_t -> prior_mean
  float*  B4     = (float*) alloc((size_t)N*D*4);  // prior_std
  (void)ws_size; (void)n_in; (void)out_size;

  float* conf = ((float*)d_out) + 1;

  const int gE  = (E + 255) / 256;
  const int gN  = (N + 255) / 256;      // also #scan blocks (196 <= 1024)
  const int gW  = (N * 64 + 255) / 256; // one wave per node
  const int gG  = (N + 63) / 64;        // GEMM row tiles

  k_detect <<<1, 256, 0, stream>>>((const u32*)eidx, flag);
  k_norm   <<<gE, 256, 0, stream>>>(eidx, flag, src_w, dst_w, E);
  k_init   <<<gN, 256, 0, stream>>>(cnt, degsc, klacc, N);
  k_hist   <<<gE, 256, 0, stream>>>(dst_w, escore, cnt, degsc, E);
  k_scan1  <<<gN, 256, 0, stream>>>(cnt, rp, bsum, N);
  k_scan2  <<<1, 1024, 0, stream>>>(bsum, gN);
  k_scan3  <<<gN, 256, 0, stream>>>(rp, cur, bsum, cnt, degsc, dinv_s, dinv_o, N, E);
  k_scatter<<<gE, 256, 0, stream>>>(src_w, dst_w, escore, cur, col, wsrt, E);

  // agg_sx = A_score x -> B1 ; agg_ox = A_ones x -> B2
  k_agg_dual<<<gW, 256, 0, stream>>>(x, rp, col, wsrt, dinv_s, dinv_o, B1, B2, N);
  // enc_t = relu(agg_sx @ W_enc + b_enc) -> B3
  k_gemm_act<<<gG, 256, 0, stream>>>(B1, W_enc, b_enc, nullptr, nullptr, 0, B3, N);
  // prior = relu(agg_ox @ W_prior + b_prior) + temb[t] -> B1
  k_gemm_act<<<gG, 256, 0, stream>>>(B2, W_pr, b_pr, temb, t_ptr, 1, B1, N);
  // agg_oe = A_ones enc_t -> B2
  k_agg_one<<<gW, 256, 0, stream>>>(B3, rp, col, dinv_o, B2, N);
  // pm = prior @ W_pm + b_pm -> B3 ; ps = sigmoid(prior @ W_ps + b_ps) -> B4
  k_gemm_dual<<<gG, 256, 0, stream>>>(B1, W_pm, b_pm, W_ps, b_ps, B3, B4, N);
  // em/es + conf_z + kl
  k_gemm_final<<<gG, 256, 0, stream>>>(B2, W_mu, b_mu, W_std, b_std, B3, B4, conf, klacc, N);
  k_finish<<<1, 64, 0, stream>>>(klacc, (float*)d_out, N);
}

// Round 4
// 551.362 us; speedup vs baseline: 1.2296x; 1.2296x over previous
//
#include <hip/hip_runtime.h>
#include <math.h>

#define D 128

typedef unsigned int u32;

__device__ __forceinline__ u32 rotl32(u32 x, int r){ return (x<<r) | (x>>(32-r)); }

// eps = jax.random.normal(jax.random.key(42), ...), element m (row-major flat).
// JAX threefry PARTITIONABLE layout: counter (hi,lo)=(0,m), key=(0,42);
// 32-bit output = x0_final ^ x1_final. Then uniform in [-1+2^-24, 1) and
// sqrt(2)*erfinv (XLA Giles polynomial).  [verified passing in R3]
__device__ __forceinline__ float jax_normal_part_xor(u32 m){
  const u32 ks0 = 0u, ks1 = 42u, ks2 = 0x1BD11BF0u; // 0x1BD11BDA ^ 0 ^ 42
  u32 x0 = 0u + ks0;
  u32 x1 = m  + ks1;
  #define TF_R4(a,b,c,d) \
    x0 += x1; x1 = rotl32(x1,(a)); x1 ^= x0; \
    x0 += x1; x1 = rotl32(x1,(b)); x1 ^= x0; \
    x0 += x1; x1 = rotl32(x1,(c)); x1 ^= x0; \
    x0 += x1; x1 = rotl32(x1,(d)); x1 ^= x0;
  TF_R4(13,15,26,6)   x0 += ks1; x1 += ks2 + 1u;
  TF_R4(17,29,16,24)  x0 += ks2; x1 += ks0 + 2u;
  TF_R4(13,15,26,6)   x0 += ks0; x1 += ks1 + 3u;
  TF_R4(17,29,16,24)  x0 += ks1; x1 += ks2 + 4u;
  TF_R4(13,15,26,6)   x0 += ks2; x1 += ks0 + 5u;
  #undef TF_R4
  u32 bits = x0 ^ x1;
  float f = __uint_as_float((bits >> 9) | 0x3F800000u) - 1.0f;   // [0,1)
  const float LO = -0.99999994f;                                  // nextafter(-1,0)
  float u = fmaxf(LO, f * 2.0f + LO);
  float w = -log1pf(-u*u);
  float p;
  if (w < 5.0f){
    w -= 2.5f;
    p =  2.81022636e-08f;
    p = fmaf(p, w,  3.43273939e-07f);
    p = fmaf(p, w, -3.5233877e-06f);
    p = fmaf(p, w, -4.39150654e-06f);
    p = fmaf(p, w,  0.00021858087f);
    p = fmaf(p, w, -0.00125372503f);
    p = fmaf(p, w, -0.00417768164f);
    p = fmaf(p, w,  0.246640727f);
    p = fmaf(p, w,  1.50140941f);
  } else {
    w = sqrtf(w) - 3.0f;
    p = -0.000200214257f;
    p = fmaf(p, w,  0.000100950558f);
    p = fmaf(p, w,  0.00134934322f);
    p = fmaf(p, w, -0.00367342844f);
    p = fmaf(p, w,  0.00573950773f);
    p = fmaf(p, w, -0.0076224613f);
    p = fmaf(p, w,  0.00943887047f);
    p = fmaf(p, w,  1.00167406f);
    p = fmaf(p, w,  2.83297682f);
  }
  return 1.41421354f * (p * u);
}

__device__ __forceinline__ float sigmoidf_(float z){ return 1.0f / (1.0f + expf(-z)); }

// ---------------- index normalization (int32 vs int64 edge_index) ----------------
__global__ void k_detect(const u32* __restrict__ e_u32, int* __restrict__ flag){
  __shared__ int s_nz;
  if (threadIdx.x == 0) s_nz = 0;
  __syncthreads();
  if (e_u32[2*threadIdx.x + 1] != 0u) atomicAdd(&s_nz, 1);
  __syncthreads();
  if (threadIdx.x == 0) *flag = (s_nz == 0) ? 1 : 0;   // all-hi-words-zero => int64
}

__global__ void k_norm(const void* __restrict__ eidx, const int* __restrict__ flag,
                       int* __restrict__ src_w, int* __restrict__ dst_w, int e){
  int i = blockIdx.x*256 + threadIdx.x;
  if (i >= e) return;
  if (*flag){
    const u32* u = (const u32*)eidx;
    src_w[i] = (int)u[2*(size_t)i];
    dst_w[i] = (int)u[2*((size_t)e + i)];
  } else {
    const int* p = (const int*)eidx;
    src_w[i] = p[i];
    dst_w[i] = p[e + i];
  }
}

// ---------------- degree / CSR build (int atomics only — native) ----------------
__global__ void k_init(int* __restrict__ cnt, int n){
  int i = blockIdx.x*256 + threadIdx.x;
  if (i < n) cnt[i] = 0;
}

__global__ void k_hist(const int* __restrict__ dst, int* __restrict__ cnt, int e){
  int i = blockIdx.x*256 + threadIdx.x;
  if (i >= e) return;
  atomicAdd(&cnt[dst[i]], 1);
}

__global__ __launch_bounds__(256) void k_scan1(const int* __restrict__ cnt,
                                               int* __restrict__ rp,
                                               int* __restrict__ bsum, int n){
  __shared__ int sh[256];
  int tid = threadIdx.x, idx = blockIdx.x*256 + tid;
  int v = (idx < n) ? cnt[idx] : 0;
  sh[tid] = v; __syncthreads();
  for (int off = 1; off < 256; off <<= 1){
    int t = (tid >= off) ? sh[tid-off] : 0;
    __syncthreads(); sh[tid] += t; __syncthreads();
  }
  if (idx < n) rp[idx] = sh[tid] - v;     // exclusive within chunk
  if (tid == 255) bsum[blockIdx.x] = sh[255];
}

__global__ __launch_bounds__(1024) void k_scan2(int* __restrict__ bsum, int nb){
  __shared__ int sh[1024];
  int tid = threadIdx.x;
  int v = (tid < nb) ? bsum[tid] : 0;
  sh[tid] = v; __syncthreads();
  for (int off = 1; off < 1024; off <<= 1){
    int t = (tid >= off) ? sh[tid-off] : 0;
    __syncthreads(); sh[tid] += t; __syncthreads();
  }
  if (tid < nb) bsum[tid] = sh[tid] - v;  // exclusive block offsets
}

__global__ void k_scan3(int* __restrict__ rp, int* __restrict__ cur,
                        const int* __restrict__ bsum, const int* __restrict__ cnt,
                        float* __restrict__ dinv_o, int n, int e){
  int idx = blockIdx.x*256 + threadIdx.x;
  if (idx < n){
    int r = rp[idx] + bsum[blockIdx.x];
    rp[idx] = r; cur[idx] = r;
    dinv_o[idx] = rsqrtf((float)(cnt[idx] + 1));
  }
  if (idx == 0) rp[n] = e;
}

__global__ void k_scatter(const int* __restrict__ src, const int* __restrict__ dst,
                          const float* __restrict__ sc, int* __restrict__ cur,
                          int* __restrict__ col, float* __restrict__ wsrt, int e){
  int i = blockIdx.x*256 + threadIdx.x;
  if (i >= e) return;
  int d = dst[i];
  int p = atomicAdd(&cur[d], 1);
  col[p] = src[i];
  wsrt[p] = sc[i];
}

// score-degree per node: 1 (self-loop) + sum of this row's edge weights. No FP atomics.
__global__ void k_deg(const int* __restrict__ rp, const float* __restrict__ wsrt,
                      float* __restrict__ dinv_s, int n){
  int i = blockIdx.x*256 + threadIdx.x;
  if (i >= n) return;
  float s = 1.0f;
  int e0 = rp[i], e1 = rp[i+1];
  for (int j = e0; j < e1; ++j) s += wsrt[j];
  dinv_s[i] = rsqrtf(s);
}

// ---------------- aggregations: one wave per node, lane holds 2 of 128 dims ----------------
__global__ __launch_bounds__(256) void k_agg_dual(
    const float* __restrict__ x, const int* __restrict__ rp,
    const int* __restrict__ col, const float* __restrict__ wsrt,
    const float* __restrict__ dinv_s, const float* __restrict__ dinv_o,
    float* __restrict__ out_s, float* __restrict__ out_o, int n){
  int wid = (blockIdx.x * 256 + threadIdx.x) >> 6;
  int lane = threadIdx.x & 63;
  if (wid >= n) return;
  const float2* x2 = (const float2*)x;
  float dsv = dinv_s[wid], dov = dinv_o[wid];
  float2 xv = x2[(size_t)wid*64 + lane];
  float ss = dsv*dsv, oo = dov*dov;                      // self-loop (w=1)
  float2 as = { xv.x*ss, xv.y*ss };
  float2 ao = { xv.x*oo, xv.y*oo };
  int e0 = rp[wid], e1 = rp[wid+1];
  for (int i = e0; i < e1; ++i){
    int s = col[i];
    float ns = dinv_s[s] * wsrt[i] * dsv;
    float no = dinv_o[s] * dov;
    float2 xs = x2[(size_t)s*64 + lane];
    as.x = fmaf(ns, xs.x, as.x); as.y = fmaf(ns, xs.y, as.y);
    ao.x = fmaf(no, xs.x, ao.x); ao.y = fmaf(no, xs.y, ao.y);
  }
  ((float2*)out_s)[(size_t)wid*64 + lane] = as;
  ((float2*)out_o)[(size_t)wid*64 + lane] = ao;
}

__global__ __launch_bounds__(256) void k_agg_one(
    const float* __restrict__ h, const int* __restrict__ rp,
    const int* __restrict__ col, const float* __restrict__ dinv_o,
    float* __restrict__ out, int n){
  int wid = (blockIdx.x * 256 + threadIdx.x) >> 6;
  int lane = threadIdx.x & 63;
  if (wid >= n) return;
  const float2* h2 = (const float2*)h;
  float dov = dinv_o[wid];
  float2 hv = h2[(size_t)wid*64 + lane];
  float oo = dov*dov;
  float2 ao = { hv.x*oo, hv.y*oo };
  int e0 = rp[wid], e1 = rp[wid+1];
  for (int i = e0; i < e1; ++i){
    int s = col[i];
    float no = dinv_o[s] * dov;
    float2 hs = h2[(size_t)s*64 + lane];
    ao.x = fmaf(no, hs.x, ao.x); ao.y = fmaf(no, hs.y, ao.y);
  }
  ((float2*)out)[(size_t)wid*64 + lane] = ao;
}

// ---------------- GEMMs: 32-row tile, block=256, thread = 4 rows x 4 cols ----------------
// 1563 blocks (~6/CU) vs 782 in R3 — grid-starvation fix.
#define GEMM_PROLOGUE(Abuf)                                                   \
  __shared__ float As[32][128];                                               \
  const int tid = threadIdx.x;                                                \
  const int row0 = blockIdx.x * 32;                                           \
  _Pragma("unroll")                                                           \
  for (int i = tid; i < 32*32; i += 256){                                     \
    int r = i >> 5, c4 = (i & 31) << 2;                                       \
    float4 v = {0.f,0.f,0.f,0.f};                                             \
    if (row0 + r < n) v = *(const float4*)((Abuf) + (size_t)(row0+r)*D + c4); \
    *(float4*)&As[r][c4] = v;                                                 \
  }                                                                           \
  __syncthreads();                                                            \
  const int tx = tid & 31, ty = tid >> 5;

__global__ __launch_bounds__(256) void k_gemm_act(
    const float* __restrict__ A, const float* __restrict__ W,
    const float* __restrict__ b, const float* __restrict__ temb,
    const int* __restrict__ t_ptr, int use_temb,
    float* __restrict__ out, int n){
  GEMM_PROLOGUE(A)
  float acc[4][4] = {};
  const float4* __restrict__ Wv = (const float4*)W;
  for (int kk = 0; kk < 128; kk += 4){
    float4 w0 = Wv[(kk+0)*32 + tx];
    float4 w1 = Wv[(kk+1)*32 + tx];
    float4 w2 = Wv[(kk+2)*32 + tx];
    float4 w3 = Wv[(kk+3)*32 + tx];
    #pragma unroll
    for (int r = 0; r < 4; ++r){
      float4 a = *(const float4*)&As[ty*4+r][kk];
      acc[r][0] = fmaf(a.x,w0.x, fmaf(a.y,w1.x, fmaf(a.z,w2.x, fmaf(a.w,w3.x, acc[r][0]))));
      acc[r][1] = fmaf(a.x,w0.y, fmaf(a.y,w1.y, fmaf(a.z,w2.y, fmaf(a.w,w3.y, acc[r][1]))));
      acc[r][2] = fmaf(a.x,w0.z, fmaf(a.y,w1.z, fmaf(a.z,w2.z, fmaf(a.w,w3.z, acc[r][2]))));
      acc[r][3] = fmaf(a.x,w0.w, fmaf(a.y,w1.w, fmaf(a.z,w2.w, fmaf(a.w,w3.w, acc[r][3]))));
    }
  }
  float4 bb = ((const float4*)b)[tx];
  float4 tt = {0.f,0.f,0.f,0.f};
  if (use_temb){ int t = *t_ptr; tt = ((const float4*)temb)[t*32 + tx]; }
  #pragma unroll
  for (int r = 0; r < 4; ++r){
    int row = row0 + ty*4 + r;
    if (row < n){
      float4 o;
      o.x = fmaxf(acc[r][0] + bb.x, 0.f) + tt.x;
      o.y = fmaxf(acc[r][1] + bb.y, 0.f) + tt.y;
      o.z = fmaxf(acc[r][2] + bb.z, 0.f) + tt.z;
      o.w = fmaxf(acc[r][3] + bb.w, 0.f) + tt.w;
      *(float4*)(out + (size_t)row*D + tx*4) = o;
    }
  }
}

// out1 = A@W1 + b1 (linear, prior_mean); out2 = sigmoid(A@W2 + b2) (prior_std)
__global__ __launch_bounds__(256) void k_gemm_dual(
    const float* __restrict__ A,
    const float* __restrict__ W1, const float* __restrict__ b1,
    const float* __restrict__ W2, const float* __restrict__ b2,
    float* __restrict__ out1, float* __restrict__ out2, int n){
  GEMM_PROLOGUE(A)
  float acc1[4][4] = {}; float acc2[4][4] = {};
  const float4* __restrict__ W1v = (const float4*)W1;
  const float4* __restrict__ W2v = (const float4*)W2;
  for (int kk = 0; kk < 128; kk += 4){
    float4 p0 = W1v[(kk+0)*32 + tx], q0 = W2v[(kk+0)*32 + tx];
    float4 p1 = W1v[(kk+1)*32 + tx], q1 = W2v[(kk+1)*32 + tx];
    float4 p2 = W1v[(kk+2)*32 + tx], q2 = W2v[(kk+2)*32 + tx];
    float4 p3 = W1v[(kk+3)*32 + tx], q3 = W2v[(kk+3)*32 + tx];
    #pragma unroll
    for (int r = 0; r < 4; ++r){
      float4 a = *(const float4*)&As[ty*4+r][kk];
      acc1[r][0] = fmaf(a.x,p0.x, fmaf(a.y,p1.x, fmaf(a.z,p2.x, fmaf(a.w,p3.x, acc1[r][0]))));
      acc1[r][1] = fmaf(a.x,p0.y, fmaf(a.y,p1.y, fmaf(a.z,p2.y, fmaf(a.w,p3.y, acc1[r][1]))));
      acc1[r][2] = fmaf(a.x,p0.z, fmaf(a.y,p1.z, fmaf(a.z,p2.z, fmaf(a.w,p3.z, acc1[r][2]))));
      acc1[r][3] = fmaf(a.x,p0.w, fmaf(a.y,p1.w, fmaf(a.z,p2.w, fmaf(a.w,p3.w, acc1[r][3]))));
      acc2[r][0] = fmaf(a.x,q0.x, fmaf(a.y,q1.x, fmaf(a.z,q2.x, fmaf(a.w,q3.x, acc2[r][0]))));
      acc2[r][1] = fmaf(a.x,q0.y, fmaf(a.y,q1.y, fmaf(a.z,q2.y, fmaf(a.w,q3.y, acc2[r][1]))));
      acc2[r][2] = fmaf(a.x,q0.z, fmaf(a.y,q1.z, fmaf(a.z,q2.z, fmaf(a.w,q3.z, acc2[r][2]))));
      acc2[r][3] = fmaf(a.x,q0.w, fmaf(a.y,q1.w, fmaf(a.z,q2.w, fmaf(a.w,q3.w, acc2[r][3]))));
    }
  }
  float4 bb1 = ((const float4*)b1)[tx];
  float4 bb2 = ((const float4*)b2)[tx];
  #pragma unroll
  for (int r = 0; r < 4; ++r){
    int row = row0 + ty*4 + r;
    if (row < n){
      float4 o1, o2;
      o1.x = acc1[r][0] + bb1.x; o1.y = acc1[r][1] + bb1.y;
      o1.z = acc1[r][2] + bb1.z; o1.w = acc1[r][3] + bb1.w;
      o2.x = sigmoidf_(acc2[r][0] + bb2.x); o2.y = sigmoidf_(acc2[r][1] + bb2.y);
      o2.z = sigmoidf_(acc2[r][2] + bb2.z); o2.w = sigmoidf_(acc2[r][3] + bb2.w);
      *(float4*)(out1 + (size_t)row*D + tx*4) = o1;
      *(float4*)(out2 + (size_t)row*D + tx*4) = o2;
    }
  }
}

// em = A@Wmu + bmu ; es = sigmoid(A@Wstd + bstd); conf = eps*es + em;
// kl partial -> pblk[block] (NO global FP atomics — they compile to CAS loops).
__global__ __launch_bounds__(256) void k_gemm_final(
    const float* __restrict__ A,
    const float* __restrict__ Wmu, const float* __restrict__ bmu,
    const float* __restrict__ Wstd, const float* __restrict__ bstd,
    const float* __restrict__ pm, const float* __restrict__ ps,
    float* __restrict__ conf, float* __restrict__ pblk, int n){
  GEMM_PROLOGUE(A)
  float acc1[4][4] = {}; float acc2[4][4] = {};
  const float4* __restrict__ W1v = (const float4*)Wmu;
  const float4* __restrict__ W2v = (const float4*)Wstd;
  for (int kk = 0; kk < 128; kk += 4){
    float4 p0 = W1v[(kk+0)*32 + tx], q0 = W2v[(kk+0)*32 + tx];
    float4 p1 = W1v[(kk+1)*32 + tx], q1 = W2v[(kk+1)*32 + tx];
    float4 p2 = W1v[(kk+2)*32 + tx], q2 = W2v[(kk+2)*32 + tx];
    float4 p3 = W1v[(kk+3)*32 + tx], q3 = W2v[(kk+3)*32 + tx];
    #pragma unroll
    for (int r = 0; r < 4; ++r){
      float4 a = *(const float4*)&As[ty*4+r][kk];
      acc1[r][0] = fmaf(a.x,p0.x, fmaf(a.y,p1.x, fmaf(a.z,p2.x, fmaf(a.w,p3.x, acc1[r][0]))));
      acc1[r][1] = fmaf(a.x,p0.y, fmaf(a.y,p1.y, fmaf(a.z,p2.y, fmaf(a.w,p3.y, acc1[r][1]))));
      acc1[r][2] = fmaf(a.x,p0.z, fmaf(a.y,p1.z, fmaf(a.z,p2.z, fmaf(a.w,p3.z, acc1[r][2]))));
      acc1[r][3] = fmaf(a.x,p0.w, fmaf(a.y,p1.w, fmaf(a.z,p2.w, fmaf(a.w,p3.w, acc1[r][3]))));
      acc2[r][0] = fmaf(a.x,q0.x, fmaf(a.y,q1.x, fmaf(a.z,q2.x, fmaf(a.w,q3.x, acc2[r][0]))));
      acc2[r][1] = fmaf(a.x,q0.y, fmaf(a.y,q1.y, fmaf(a.z,q2.y, fmaf(a.w,q3.y, acc2[r][1]))));
      acc2[r][2] = fmaf(a.x,q0.z, fmaf(a.y,q1.z, fmaf(a.z,q2.z, fmaf(a.w,q3.z, acc2[r][2]))));
      acc2[r][3] = fmaf(a.x,q0.w, fmaf(a.y,q1.w, fmaf(a.z,q2.w, fmaf(a.w,q3.w, acc2[r][3]))));
    }
  }
  float4 bb1 = ((const float4*)bmu)[tx];
  float4 bb2 = ((const float4*)bstd)[tx];
  const float EPS = 1e-9f;
  float klsum = 0.f;
  #pragma unroll
  for (int r = 0; r < 4; ++r){
    int row = row0 + ty*4 + r;
    if (row < n){
      float4 pmv = *(const float4*)(pm + (size_t)row*D + tx*4);
      float4 psv = *(const float4*)(ps + (size_t)row*D + tx*4);
      float em[4], es[4], pmf[4] = {pmv.x,pmv.y,pmv.z,pmv.w}, psf[4] = {psv.x,psv.y,psv.z,psv.w};
      float bmu4[4] = {bb1.x,bb1.y,bb1.z,bb1.w}, bsd4[4] = {bb2.x,bb2.y,bb2.z,bb2.w};
      #pragma unroll
      for (int c = 0; c < 4; ++c){
        em[c] = acc1[r][c] + bmu4[c];
        es[c] = sigmoidf_(acc2[r][c] + bsd4[c]);
        u32 m = (u32)row*128u + (u32)(tx*4 + c);
        float eps = jax_normal_part_xor(m);
        conf[m] = fmaf(eps, es[c], em[c]);
        float es_e = es[c] + EPS, ps_e = psf[c] + EPS;
        float diff = em[c] - pmf[c];
        klsum += 2.0f*(logf(ps_e) - logf(es_e))
               + (es_e*es_e + diff*diff) / (ps_e*ps_e) - 1.0f;
      }
    }
  }
  // wave shfl reduce -> LDS -> one write per block
  #pragma unroll
  for (int off = 32; off > 0; off >>= 1) klsum += __shfl_down(klsum, off);
  __shared__ float wsum[4];
  if ((tid & 63) == 0) wsum[tid >> 6] = klsum;
  __syncthreads();
  if (tid == 0) pblk[blockIdx.x] = wsum[0] + wsum[1] + wsum[2] + wsum[3];
}

__global__ __launch_bounds__(256) void k_finish(const float* __restrict__ pblk, int nb,
                                                float* __restrict__ out0, int n){
  __shared__ double sh[256];
  double s = 0.0;
  for (int i = threadIdx.x; i < nb; i += 256) s += (double)pblk[i];
  sh[threadIdx.x] = s; __syncthreads();
  for (int off = 128; off > 0; off >>= 1){
    if (threadIdx.x < off) sh[threadIdx.x] += sh[threadIdx.x + off];
    __syncthreads();
  }
  if (threadIdx.x == 0) out0[0] = (float)(0.5 * sh[0] / (double)n);
}

// ---------------------------------------------------------------------------
extern "C" void kernel_launch(void* const* d_in, const int* in_sizes, int n_in,
                              void* d_out, int out_size, void* d_ws, size_t ws_size,
                              hipStream_t stream){
  const void*  eidx   = d_in[0];
  const float* x      = (const float*)d_in[1];
  const int*   t_ptr  = (const int*)d_in[2];
  const float* escore = (const float*)d_in[3];
  const float* W_enc = (const float*)d_in[6];  const float* b_enc = (const float*)d_in[7];
  const float* W_mu  = (const float*)d_in[8];  const float* b_mu  = (const float*)d_in[9];
  const float* W_std = (const float*)d_in[10]; const float* b_std = (const float*)d_in[11];
  const float* W_pr  = (const float*)d_in[12]; const float* b_pr  = (const float*)d_in[13];
  const float* W_pm  = (const float*)d_in[14]; const float* b_pm  = (const float*)d_in[15];
  const float* W_ps  = (const float*)d_in[16]; const float* b_ps  = (const float*)d_in[17];
  const float* temb  = (const float*)d_in[18];

  const int N = in_sizes[1] / D;
  const int E = in_sizes[3];

  char* w = (char*)d_ws;
  auto alloc = [&](size_t bytes) -> char* {
    char* p = w; w += (bytes + 255) & ~(size_t)255; return p;
  };
  int*    flag   = (int*)   alloc(256);
  int*    src_w  = (int*)   alloc((size_t)E*4);
  int*    dst_w  = (int*)   alloc((size_t)E*4);
  int*    cnt    = (int*)   alloc((size_t)N*4);
  int*    rp     = (int*)   alloc((size_t)(N+1)*4);
  int*    cur    = (int*)   alloc((size_t)N*4);
  float*  dinv_s = (float*) alloc((size_t)N*4);
  float*  dinv_o = (float*) alloc((size_t)N*4);
  int*    bsum   = (int*)   alloc(1024*4);
  int*    col    = (int*)   alloc((size_t)E*4);
  float*  wsrt   = (float*) alloc((size_t)E*4);
  float*  B1     = (float*) alloc((size_t)N*D*4);  // agg_score_x -> prior
  float*  B2     = (float*) alloc((size_t)N*D*4);  // agg_ones_x  -> agg_ones_enc
  float*  B3     = (float*) alloc((size_t)N*D*4);  // enc_t -> prior_mean
  float*  B4     = (float*) alloc((size_t)N*D*4);  // prior_std
  const int gG   = (N + 31) / 32;                  // GEMM row tiles (32 rows)
  float*  pblk   = (float*) alloc((size_t)gG*4);   // per-block kl partials
  (void)ws_size; (void)n_in; (void)out_size;

  float* conf = ((float*)d_out) + 1;

  const int gE  = (E + 255) / 256;
  const int gN  = (N + 255) / 256;      // also #scan blocks (196 <= 1024)
  const int gW  = (N * 64 + 255) / 256; // one wave per node

  k_detect <<<1, 256, 0, stream>>>((const u32*)eidx, flag);
  k_norm   <<<gE, 256, 0, stream>>>(eidx, flag, src_w, dst_w, E);
  k_init   <<<gN, 256, 0, stream>>>(cnt, N);
  k_hist   <<<gE, 256, 0, stream>>>(dst_w, cnt, E);
  k_scan1  <<<gN, 256, 0, stream>>>(cnt, rp, bsum, N);
  k_scan2  <<<1, 1024, 0, stream>>>(bsum, gN);
  k_scan3  <<<gN, 256, 0, stream>>>(rp, cur, bsum, cnt, dinv_o, N, E);
  k_scatter<<<gE, 256, 0, stream>>>(src_w, dst_w, escore, cur, col, wsrt, E);
  k_deg    <<<gN, 256, 0, stream>>>(rp, wsrt, dinv_s, N);

  // agg_sx = A_score x -> B1 ; agg_ox = A_ones x -> B2
  k_agg_dual<<<gW, 256, 0, stream>>>(x, rp, col, wsrt, dinv_s, dinv_o, B1, B2, N);
  // enc_t = relu(agg_sx @ W_enc + b_enc) -> B3
  k_gemm_act<<<gG, 256, 0, stream>>>(B1, W_enc, b_enc, nullptr, nullptr, 0, B3, N);
  // prior = relu(agg_ox @ W_prior + b_prior) + temb[t] -> B1
  k_gemm_act<<<gG, 256, 0, stream>>>(B2, W_pr, b_pr, temb, t_ptr, 1, B1, N);
  // agg_oe = A_ones enc_t -> B2
  k_agg_one<<<gW, 256, 0, stream>>>(B3, rp, col, dinv_o, B2, N);
  // pm = prior @ W_pm + b_pm -> B3 ; ps = sigmoid(prior @ W_ps + b_ps) -> B4
  k_gemm_dual<<<gG, 256, 0, stream>>>(B1, W_pm, b_pm, W_ps, b_ps, B3, B4, N);
  // em/es + conf_z + kl partials
  k_gemm_final<<<gG, 256, 0, stream>>>(B2, W_mu, b_mu, W_std, b_std, B3, B4, conf, pblk, N);
  k_finish<<<1, 256, 0, stream>>>(pblk, gG, (float*)d_out, N);
}

// Round 5
// 465.442 us; speedup vs baseline: 1.4566x; 1.1846x over previous
//
#include <hip/hip_runtime.h>
#include <math.h>

#define D 128

typedef unsigned int u32;

__device__ __forceinline__ u32 rotl32(u32 x, int r){ return (x<<r) | (x>>(32-r)); }

// eps = jax.random.normal(jax.random.key(42), ...), element m (row-major flat).
// JAX threefry PARTITIONABLE layout: counter (hi,lo)=(0,m), key=(0,42);
// 32-bit output = x0_final ^ x1_final. Then uniform in [-1+2^-24, 1) and
// sqrt(2)*erfinv (XLA Giles polynomial).  [verified bit-correct in R3]
__device__ __forceinline__ float jax_normal_part_xor(u32 m){
  const u32 ks0 = 0u, ks1 = 42u, ks2 = 0x1BD11BF0u; // 0x1BD11BDA ^ 0 ^ 42
  u32 x0 = 0u + ks0;
  u32 x1 = m  + ks1;
  #define TF_R4(a,b,c,d) \
    x0 += x1; x1 = rotl32(x1,(a)); x1 ^= x0; \
    x0 += x1; x1 = rotl32(x1,(b)); x1 ^= x0; \
    x0 += x1; x1 = rotl32(x1,(c)); x1 ^= x0; \
    x0 += x1; x1 = rotl32(x1,(d)); x1 ^= x0;
  TF_R4(13,15,26,6)   x0 += ks1; x1 += ks2 + 1u;
  TF_R4(17,29,16,24)  x0 += ks2; x1 += ks0 + 2u;
  TF_R4(13,15,26,6)   x0 += ks0; x1 += ks1 + 3u;
  TF_R4(17,29,16,24)  x0 += ks1; x1 += ks2 + 4u;
  TF_R4(13,15,26,6)   x0 += ks2; x1 += ks0 + 5u;
  #undef TF_R4
  u32 bits = x0 ^ x1;
  float f = __uint_as_float((bits >> 9) | 0x3F800000u) - 1.0f;   // [0,1)
  const float LO = -0.99999994f;                                  // nextafter(-1,0)
  float u = fmaxf(LO, f * 2.0f + LO);
  float w = -log1pf(-u*u);
  float p;
  if (w < 5.0f){
    w -= 2.5f;
    p =  2.81022636e-08f;
    p = fmaf(p, w,  3.43273939e-07f);
    p = fmaf(p, w, -3.5233877e-06f);
    p = fmaf(p, w, -4.39150654e-06f);
    p = fmaf(p, w,  0.00021858087f);
    p = fmaf(p, w, -0.00125372503f);
    p = fmaf(p, w, -0.00417768164f);
    p = fmaf(p, w,  0.246640727f);
    p = fmaf(p, w,  1.50140941f);
  } else {
    w = sqrtf(w) - 3.0f;
    p = -0.000200214257f;
    p = fmaf(p, w,  0.000100950558f);
    p = fmaf(p, w,  0.00134934322f);
    p = fmaf(p, w, -0.00367342844f);
    p = fmaf(p, w,  0.00573950773f);
    p = fmaf(p, w, -0.0076224613f);
    p = fmaf(p, w,  0.00943887047f);
    p = fmaf(p, w,  1.00167406f);
    p = fmaf(p, w,  2.83297682f);
  }
  return 1.41421354f * (p * u);
}

__device__ __forceinline__ float sigmoidf_(float z){ return 1.0f / (1.0f + __expf(-z)); }

// ---------------- index normalization (int32 vs int64 edge_index) ----------------
__global__ void k_detect(const u32* __restrict__ e_u32, int* __restrict__ flag){
  __shared__ int s_nz;
  if (threadIdx.x == 0) s_nz = 0;
  __syncthreads();
  if (e_u32[2*threadIdx.x + 1] != 0u) atomicAdd(&s_nz, 1);
  __syncthreads();
  if (threadIdx.x == 0) *flag = (s_nz == 0) ? 1 : 0;   // all-hi-words-zero => int64
}

__global__ void k_norm(const void* __restrict__ eidx, const int* __restrict__ flag,
                       int* __restrict__ src_w, int* __restrict__ dst_w, int e){
  int i = blockIdx.x*256 + threadIdx.x;
  if (i >= e) return;
  if (*flag){
    const u32* u = (const u32*)eidx;
    src_w[i] = (int)u[2*(size_t)i];
    dst_w[i] = (int)u[2*((size_t)e + i)];
  } else {
    const int* p = (const int*)eidx;
    src_w[i] = p[i];
    dst_w[i] = p[e + i];
  }
}

// ---------------- degree / CSR build (int atomics only — native) ----------------
__global__ void k_init(int* __restrict__ cnt, int n){
  int i = blockIdx.x*256 + threadIdx.x;
  if (i < n) cnt[i] = 0;
}

__global__ void k_hist(const int* __restrict__ dst, int* __restrict__ cnt, int e){
  int i = blockIdx.x*256 + threadIdx.x;
  if (i >= e) return;
  atomicAdd(&cnt[dst[i]], 1);
}

__global__ __launch_bounds__(256) void k_scan1(const int* __restrict__ cnt,
                                               int* __restrict__ rp,
                                               int* __restrict__ bsum, int n){
  __shared__ int sh[256];
  int tid = threadIdx.x, idx = blockIdx.x*256 + tid;
  int v = (idx < n) ? cnt[idx] : 0;
  sh[tid] = v; __syncthreads();
  for (int off = 1; off < 256; off <<= 1){
    int t = (tid >= off) ? sh[tid-off] : 0;
    __syncthreads(); sh[tid] += t; __syncthreads();
  }
  if (idx < n) rp[idx] = sh[tid] - v;     // exclusive within chunk
  if (tid == 255) bsum[blockIdx.x] = sh[255];
}

__global__ __launch_bounds__(1024) void k_scan2(int* __restrict__ bsum, int nb){
  __shared__ int sh[1024];
  int tid = threadIdx.x;
  int v = (tid < nb) ? bsum[tid] : 0;
  sh[tid] = v; __syncthreads();
  for (int off = 1; off < 1024; off <<= 1){
    int t = (tid >= off) ? sh[tid-off] : 0;
    __syncthreads(); sh[tid] += t; __syncthreads();
  }
  if (tid < nb) bsum[tid] = sh[tid] - v;  // exclusive block offsets
}

__global__ void k_scan3(int* __restrict__ rp, int* __restrict__ cur,
                        const int* __restrict__ bsum, const int* __restrict__ cnt,
                        float* __restrict__ dinv_o, int n, int e){
  int idx = blockIdx.x*256 + threadIdx.x;
  if (idx < n){
    int r = rp[idx] + bsum[blockIdx.x];
    rp[idx] = r; cur[idx] = r;
    dinv_o[idx] = rsqrtf((float)(cnt[idx] + 1));
  }
  if (idx == 0) rp[n] = e;
}

__global__ void k_scatter(const int* __restrict__ src, const int* __restrict__ dst,
                          const float* __restrict__ sc, int* __restrict__ cur,
                          int* __restrict__ col, float* __restrict__ wsrt, int e){
  int i = blockIdx.x*256 + threadIdx.x;
  if (i >= e) return;
  int d = dst[i];
  int p = atomicAdd(&cur[d], 1);
  col[p] = src[i];
  wsrt[p] = sc[i];
}

// score-degree per node: 1 (self-loop) + sum of this row's edge weights. No FP atomics.
__global__ void k_deg(const int* __restrict__ rp, const float* __restrict__ wsrt,
                      float* __restrict__ dinv_s, int n){
  int i = blockIdx.x*256 + threadIdx.x;
  if (i >= n) return;
  float s = 1.0f;
  int e0 = rp[i], e1 = rp[i+1];
  for (int j = e0; j < e1; ++j) s += wsrt[j];
  dinv_s[i] = rsqrtf(s);
}

// ---------------- aggregations: one wave per node ----------------
// Metadata (col, weight, dinv) loaded 64-edges-at-a-time in ONE parallel round,
// then broadcast via shfl; row gathers 4x unrolled for MLP.
__global__ __launch_bounds__(256) void k_agg_dual(
    const float* __restrict__ x, const int* __restrict__ rp,
    const int* __restrict__ col, const float* __restrict__ wsrt,
    const float* __restrict__ dinv_s, const float* __restrict__ dinv_o,
    float* __restrict__ out_s, float* __restrict__ out_o, int n){
  int wid = (blockIdx.x * 256 + threadIdx.x) >> 6;
  int lane = threadIdx.x & 63;
  if (wid >= n) return;
  const float2* x2 = (const float2*)x;
  float dsv = dinv_s[wid], dov = dinv_o[wid];
  float2 xv = x2[(size_t)wid*64 + lane];
  float ss = dsv*dsv, oo = dov*dov;                      // self-loop (w=1)
  float2 as = { xv.x*ss, xv.y*ss };
  float2 ao = { xv.x*oo, xv.y*oo };
  int e0 = rp[wid], e1 = rp[wid+1];
  for (int base = e0; base < e1; base += 64){
    int cnt = e1 - base; if (cnt > 64) cnt = 64;
    int idx = base + (lane < cnt ? lane : cnt - 1);
    int   sl = col[idx];
    float wl = wsrt[idx];
    float nsl = dinv_s[sl] * wl * dsv;
    float nol = dinv_o[sl] * dov;
    int j = 0;
    for (; j + 4 <= cnt; j += 4){
      int   s0=__shfl(sl,j),   s1=__shfl(sl,j+1),   s2=__shfl(sl,j+2),   s3=__shfl(sl,j+3);
      float a0=__shfl(nsl,j),  a1=__shfl(nsl,j+1),  a2=__shfl(nsl,j+2),  a3=__shfl(nsl,j+3);
      float b0=__shfl(nol,j),  b1=__shfl(nol,j+1),  b2=__shfl(nol,j+2),  b3=__shfl(nol,j+3);
      float2 r0 = x2[(size_t)s0*64 + lane];
      float2 r1 = x2[(size_t)s1*64 + lane];
      float2 r2 = x2[(size_t)s2*64 + lane];
      float2 r3 = x2[(size_t)s3*64 + lane];
      as.x = fmaf(a0,r0.x,as.x); as.y = fmaf(a0,r0.y,as.y);
      ao.x = fmaf(b0,r0.x,ao.x); ao.y = fmaf(b0,r0.y,ao.y);
      as.x = fmaf(a1,r1.x,as.x); as.y = fmaf(a1,r1.y,as.y);
      ao.x = fmaf(b1,r1.x,ao.x); ao.y = fmaf(b1,r1.y,ao.y);
      as.x = fmaf(a2,r2.x,as.x); as.y = fmaf(a2,r2.y,as.y);
      ao.x = fmaf(b2,r2.x,ao.x); ao.y = fmaf(b2,r2.y,ao.y);
      as.x = fmaf(a3,r3.x,as.x); as.y = fmaf(a3,r3.y,as.y);
      ao.x = fmaf(b3,r3.x,ao.x); ao.y = fmaf(b3,r3.y,ao.y);
    }
    for (; j < cnt; ++j){
      int   s0=__shfl(sl,j);
      float a0=__shfl(nsl,j), b0=__shfl(nol,j);
      float2 r0 = x2[(size_t)s0*64 + lane];
      as.x = fmaf(a0,r0.x,as.x); as.y = fmaf(a0,r0.y,as.y);
      ao.x = fmaf(b0,r0.x,ao.x); ao.y = fmaf(b0,r0.y,ao.y);
    }
  }
  ((float2*)out_s)[(size_t)wid*64 + lane] = as;
  ((float2*)out_o)[(size_t)wid*64 + lane] = ao;
}

__global__ __launch_bounds__(256) void k_agg_one(
    const float* __restrict__ h, const int* __restrict__ rp,
    const int* __restrict__ col, const float* __restrict__ dinv_o,
    float* __restrict__ out, int n){
  int wid = (blockIdx.x * 256 + threadIdx.x) >> 6;
  int lane = threadIdx.x & 63;
  if (wid >= n) return;
  const float2* h2 = (const float2*)h;
  float dov = dinv_o[wid];
  float2 hv = h2[(size_t)wid*64 + lane];
  float oo = dov*dov;
  float2 ao = { hv.x*oo, hv.y*oo };
  int e0 = rp[wid], e1 = rp[wid+1];
  for (int base = e0; base < e1; base += 64){
    int cnt = e1 - base; if (cnt > 64) cnt = 64;
    int idx = base + (lane < cnt ? lane : cnt - 1);
    int   sl = col[idx];
    float nol = dinv_o[sl] * dov;
    int j = 0;
    for (; j + 4 <= cnt; j += 4){
      int   s0=__shfl(sl,j),  s1=__shfl(sl,j+1),  s2=__shfl(sl,j+2),  s3=__shfl(sl,j+3);
      float b0=__shfl(nol,j), b1=__shfl(nol,j+1), b2=__shfl(nol,j+2), b3=__shfl(nol,j+3);
      float2 r0 = h2[(size_t)s0*64 + lane];
      float2 r1 = h2[(size_t)s1*64 + lane];
      float2 r2 = h2[(size_t)s2*64 + lane];
      float2 r3 = h2[(size_t)s3*64 + lane];
      ao.x = fmaf(b0,r0.x,ao.x); ao.y = fmaf(b0,r0.y,ao.y);
      ao.x = fmaf(b1,r1.x,ao.x); ao.y = fmaf(b1,r1.y,ao.y);
      ao.x = fmaf(b2,r2.x,ao.x); ao.y = fmaf(b2,r2.y,ao.y);
      ao.x = fmaf(b3,r3.x,ao.x); ao.y = fmaf(b3,r3.y,ao.y);
    }
    for (; j < cnt; ++j){
      int   s0=__shfl(sl,j);
      float b0=__shfl(nol,j);
      float2 r0 = h2[(size_t)s0*64 + lane];
      ao.x = fmaf(b0,r0.x,ao.x); ao.y = fmaf(b0,r0.y,ao.y);
    }
  }
  ((float2*)out)[(size_t)wid*64 + lane] = ao;
}

// ---------------- GEMMs: 32-row tile, block=256, thread = 4 rows x 4 cols ----------
// W chunks register-prefetched one kk-step ahead (L2 latency hides under 128 FMAs).
#define GEMM_PROLOGUE(Abuf)                                                   \
  __shared__ float As[32][128];                                               \
  const int tid = threadIdx.x;                                                \
  const int row0 = blockIdx.x * 32;                                           \
  _Pragma("unroll")                                                           \
  for (int i = tid; i < 32*32; i += 256){                                     \
    int r = i >> 5, c4 = (i & 31) << 2;                                       \
    float4 v = {0.f,0.f,0.f,0.f};                                             \
    if (row0 + r < n) v = *(const float4*)((Abuf) + (size_t)(row0+r)*D + c4); \
    *(float4*)&As[r][c4] = v;                                                 \
  }                                                                           \
  __syncthreads();                                                            \
  const int tx = tid & 31, ty = tid >> 5;

#define FMA4(accr, a, w0,w1,w2,w3) \
  accr[0] = fmaf(a.x,w0.x, fmaf(a.y,w1.x, fmaf(a.z,w2.x, fmaf(a.w,w3.x, accr[0])))); \
  accr[1] = fmaf(a.x,w0.y, fmaf(a.y,w1.y, fmaf(a.z,w2.y, fmaf(a.w,w3.y, accr[1])))); \
  accr[2] = fmaf(a.x,w0.z, fmaf(a.y,w1.z, fmaf(a.z,w2.z, fmaf(a.w,w3.z, accr[2])))); \
  accr[3] = fmaf(a.x,w0.w, fmaf(a.y,w1.w, fmaf(a.z,w2.w, fmaf(a.w,w3.w, accr[3]))));

// Two independent act-GEMMs in one launch (blockIdx.y selects slice).
// y=0: out0 = relu(A0@W0 + b0);  y=1: out1 = relu(A1@W1 + b1) + temb[t]
__global__ __launch_bounds__(256) void k_gemm_act2(
    const float* __restrict__ A0, const float* __restrict__ W0, const float* __restrict__ b0,
    const float* __restrict__ A1, const float* __restrict__ W1, const float* __restrict__ b1,
    const float* __restrict__ temb, const int* __restrict__ t_ptr,
    float* __restrict__ out0, float* __restrict__ out1, int n){
  const int sl = blockIdx.y;
  const float* A = sl ? A1 : A0;
  const float* W = sl ? W1 : W0;
  const float* b = sl ? b1 : b0;
  float* out     = sl ? out1 : out0;
  GEMM_PROLOGUE(A)
  float acc[4][4] = {};
  const float4* __restrict__ Wv = (const float4*)W;
  float4 w0 = Wv[0*32+tx], w1 = Wv[1*32+tx], w2 = Wv[2*32+tx], w3 = Wv[3*32+tx];
  for (int kk = 0; kk < 124; kk += 4){
    float4 n0 = Wv[(kk+4)*32+tx], n1 = Wv[(kk+5)*32+tx],
           n2 = Wv[(kk+6)*32+tx], n3 = Wv[(kk+7)*32+tx];
    #pragma unroll
    for (int r = 0; r < 4; ++r){
      float4 a = *(const float4*)&As[ty*4+r][kk];
      FMA4(acc[r], a, w0,w1,w2,w3)
    }
    w0=n0; w1=n1; w2=n2; w3=n3;
  }
  #pragma unroll
  for (int r = 0; r < 4; ++r){
    float4 a = *(const float4*)&As[ty*4+r][124];
    FMA4(acc[r], a, w0,w1,w2,w3)
  }
  float4 bb = ((const float4*)b)[tx];
  float4 tt = {0.f,0.f,0.f,0.f};
  if (sl){ int t = *t_ptr; tt = ((const float4*)temb)[t*32 + tx]; }
  #pragma unroll
  for (int r = 0; r < 4; ++r){
    int row = row0 + ty*4 + r;
    if (row < n){
      float4 o;
      o.x = fmaxf(acc[r][0] + bb.x, 0.f) + tt.x;
      o.y = fmaxf(acc[r][1] + bb.y, 0.f) + tt.y;
      o.z = fmaxf(acc[r][2] + bb.z, 0.f) + tt.z;
      o.w = fmaxf(acc[r][3] + bb.w, 0.f) + tt.w;
      *(float4*)(out + (size_t)row*D + tx*4) = o;
    }
  }
}

// out1 = A@W1 + b1 (linear, prior_mean); out2 = sigmoid(A@W2 + b2) (prior_std)
__global__ __launch_bounds__(256) void k_gemm_dual(
    const float* __restrict__ A,
    const float* __restrict__ W1, const float* __restrict__ b1,
    const float* __restrict__ W2, const float* __restrict__ b2,
    float* __restrict__ out1, float* __restrict__ out2, int n){
  GEMM_PROLOGUE(A)
  float acc1[4][4] = {}; float acc2[4][4] = {};
  const float4* __restrict__ W1v = (const float4*)W1;
  const float4* __restrict__ W2v = (const float4*)W2;
  float4 p0=W1v[0*32+tx], p1=W1v[1*32+tx], p2=W1v[2*32+tx], p3=W1v[3*32+tx];
  float4 q0=W2v[0*32+tx], q1=W2v[1*32+tx], q2=W2v[2*32+tx], q3=W2v[3*32+tx];
  for (int kk = 0; kk < 124; kk += 4){
    float4 np0=W1v[(kk+4)*32+tx], np1=W1v[(kk+5)*32+tx],
           np2=W1v[(kk+6)*32+tx], np3=W1v[(kk+7)*32+tx];
    float4 nq0=W2v[(kk+4)*32+tx], nq1=W2v[(kk+5)*32+tx],
           nq2=W2v[(kk+6)*32+tx], nq3=W2v[(kk+7)*32+tx];
    #pragma unroll
    for (int r = 0; r < 4; ++r){
      float4 a = *(const float4*)&As[ty*4+r][kk];
      FMA4(acc1[r], a, p0,p1,p2,p3)
      FMA4(acc2[r], a, q0,q1,q2,q3)
    }
    p0=np0; p1=np1; p2=np2; p3=np3;
    q0=nq0; q1=nq1; q2=nq2; q3=nq3;
  }
  #pragma unroll
  for (int r = 0; r < 4; ++r){
    float4 a = *(const float4*)&As[ty*4+r][124];
    FMA4(acc1[r], a, p0,p1,p2,p3)
    FMA4(acc2[r], a, q0,q1,q2,q3)
  }
  float4 bb1 = ((const float4*)b1)[tx];
  float4 bb2 = ((const float4*)b2)[tx];
  #pragma unroll
  for (int r = 0; r < 4; ++r){
    int row = row0 + ty*4 + r;
    if (row < n){
      float4 o1, o2;
      o1.x = acc1[r][0] + bb1.x; o1.y = acc1[r][1] + bb1.y;
      o1.z = acc1[r][2] + bb1.z; o1.w = acc1[r][3] + bb1.w;
      o2.x = sigmoidf_(acc2[r][0] + bb2.x); o2.y = sigmoidf_(acc2[r][1] + bb2.y);
      o2.z = sigmoidf_(acc2[r][2] + bb2.z); o2.w = sigmoidf_(acc2[r][3] + bb2.w);
      *(float4*)(out1 + (size_t)row*D + tx*4) = o1;
      *(float4*)(out2 + (size_t)row*D + tx*4) = o2;
    }
  }
}

// em = A@Wmu + bmu ; es = sigmoid(A@Wstd + bstd); conf = eps*es + em;
// kl partial -> pblk[block] (no global FP atomics).
__global__ __launch_bounds__(256) void k_gemm_final(
    const float* __restrict__ A,
    const float* __restrict__ Wmu, const float* __restrict__ bmu,
    const float* __restrict__ Wstd, const float* __restrict__ bstd,
    const float* __restrict__ pm, const float* __restrict__ ps,
    float* __restrict__ conf, float* __restrict__ pblk, int n){
  GEMM_PROLOGUE(A)
  float acc1[4][4] = {}; float acc2[4][4] = {};
  const float4* __restrict__ W1v = (const float4*)Wmu;
  const float4* __restrict__ W2v = (const float4*)Wstd;
  float4 p0=W1v[0*32+tx], p1=W1v[1*32+tx], p2=W1v[2*32+tx], p3=W1v[3*32+tx];
  float4 q0=W2v[0*32+tx], q1=W2v[1*32+tx], q2=W2v[2*32+tx], q3=W2v[3*32+tx];
  for (int kk = 0; kk < 124; kk += 4){
    float4 np0=W1v[(kk+4)*32+tx], np1=W1v[(kk+5)*32+tx],
           np2=W1v[(kk+6)*32+tx], np3=W1v[(kk+7)*32+tx];
    float4 nq0=W2v[(kk+4)*32+tx], nq1=W2v[(kk+5)*32+tx],
           nq2=W2v[(kk+6)*32+tx], nq3=W2v[(kk+7)*32+tx];
    #pragma unroll
    for (int r = 0; r < 4; ++r){
      float4 a = *(const float4*)&As[ty*4+r][kk];
      FMA4(acc1[r], a, p0,p1,p2,p3)
      FMA4(acc2[r], a, q0,q1,q2,q3)
    }
    p0=np0; p1=np1; p2=np2; p3=np3;
    q0=nq0; q1=nq1; q2=nq2; q3=nq3;
  }
  #pragma unroll
  for (int r = 0; r < 4; ++r){
    float4 a = *(const float4*)&As[ty*4+r][124];
    FMA4(acc1[r], a, p0,p1,p2,p3)
    FMA4(acc2[r], a, q0,q1,q2,q3)
  }
  float4 bb1 = ((const float4*)bmu)[tx];
  float4 bb2 = ((const float4*)bstd)[tx];
  const float EPS = 1e-9f;
  float klsum = 0.f;
  #pragma unroll
  for (int r = 0; r < 4; ++r){
    int row = row0 + ty*4 + r;
    if (row < n){
      float4 pmv = *(const float4*)(pm + (size_t)row*D + tx*4);
      float4 psv = *(const float4*)(ps + (size_t)row*D + tx*4);
      float em[4], es[4], pmf[4] = {pmv.x,pmv.y,pmv.z,pmv.w}, psf[4] = {psv.x,psv.y,psv.z,psv.w};
      float bmu4[4] = {bb1.x,bb1.y,bb1.z,bb1.w}, bsd4[4] = {bb2.x,bb2.y,bb2.z,bb2.w};
      #pragma unroll
      for (int c = 0; c < 4; ++c){
        em[c] = acc1[r][c] + bmu4[c];
        es[c] = sigmoidf_(acc2[r][c] + bsd4[c]);
        u32 m = (u32)row*128u + (u32)(tx*4 + c);
        float eps = jax_normal_part_xor(m);
        conf[m] = fmaf(eps, es[c], em[c]);
        float es_e = es[c] + EPS, ps_e = psf[c] + EPS;
        float diff = em[c] - pmf[c];
        klsum += 2.0f*__logf(ps_e/es_e)
               + (es_e*es_e + diff*diff) / (ps_e*ps_e) - 1.0f;
      }
    }
  }
  // wave shfl reduce -> LDS -> one write per block
  #pragma unroll
  for (int off = 32; off > 0; off >>= 1) klsum += __shfl_down(klsum, off);
  __shared__ float wsum[4];
  if ((tid & 63) == 0) wsum[tid >> 6] = klsum;
  __syncthreads();
  if (tid == 0) pblk[blockIdx.x] = wsum[0] + wsum[1] + wsum[2] + wsum[3];
}

__global__ __launch_bounds__(256) void k_finish(const float* __restrict__ pblk, int nb,
                                                float* __restrict__ out0, int n){
  __shared__ double sh[256];
  double s = 0.0;
  for (int i = threadIdx.x; i < nb; i += 256) s += (double)pblk[i];
  sh[threadIdx.x] = s; __syncthreads();
  for (int off = 128; off > 0; off >>= 1){
    if (threadIdx.x < off) sh[threadIdx.x] += sh[threadIdx.x + off];
    __syncthreads();
  }
  if (threadIdx.x == 0) out0[0] = (float)(0.5 * sh[0] / (double)n);
}

// ---------------------------------------------------------------------------
extern "C" void kernel_launch(void* const* d_in, const int* in_sizes, int n_in,
                              void* d_out, int out_size, void* d_ws, size_t ws_size,
                              hipStream_t stream){
  const void*  eidx   = d_in[0];
  const float* x      = (const float*)d_in[1];
  const int*   t_ptr  = (const int*)d_in[2];
  const float* escore = (const float*)d_in[3];
  const float* W_enc = (const float*)d_in[6];  const float* b_enc = (const float*)d_in[7];
  const float* W_mu  = (const float*)d_in[8];  const float* b_mu  = (const float*)d_in[9];
  const float* W_std = (const float*)d_in[10]; const float* b_std = (const float*)d_in[11];
  const float* W_pr  = (const float*)d_in[12]; const float* b_pr  = (const float*)d_in[13];
  const float* W_pm  = (const float*)d_in[14]; const float* b_pm  = (const float*)d_in[15];
  const float* W_ps  = (const float*)d_in[16]; const float* b_ps  = (const float*)d_in[17];
  const float* temb  = (const float*)d_in[18];

  const int N = in_sizes[1] / D;
  const int E = in_sizes[3];

  char* w = (char*)d_ws;
  auto alloc = [&](size_t bytes) -> char* {
    char* p = w; w += (bytes + 255) & ~(size_t)255; return p;
  };
  int*    flag   = (int*)   alloc(256);
  int*    src_w  = (int*)   alloc((size_t)E*4);
  int*    dst_w  = (int*)   alloc((size_t)E*4);
  int*    cnt    = (int*)   alloc((size_t)N*4);
  int*    rp     = (int*)   alloc((size_t)(N+1)*4);
  int*    cur    = (int*)   alloc((size_t)N*4);
  float*  dinv_s = (float*) alloc((size_t)N*4);
  float*  dinv_o = (float*) alloc((size_t)N*4);
  int*    bsum   = (int*)   alloc(1024*4);
  int*    col    = (int*)   alloc((size_t)E*4);
  float*  wsrt   = (float*) alloc((size_t)E*4);
  float*  B1     = (float*) alloc((size_t)N*D*4);  // agg_score_x
  float*  B2     = (float*) alloc((size_t)N*D*4);  // agg_ones_x -> agg_ones_enc
  float*  B3     = (float*) alloc((size_t)N*D*4);  // enc_t -> prior_mean
  float*  B4     = (float*) alloc((size_t)N*D*4);  // prior_std
  float*  B5     = (float*) alloc((size_t)N*D*4);  // prior
  const int gG   = (N + 31) / 32;                  // GEMM row tiles (32 rows)
  float*  pblk   = (float*) alloc((size_t)gG*4);   // per-block kl partials
  (void)ws_size; (void)n_in; (void)out_size;

  float* conf = ((float*)d_out) + 1;

  const int gE  = (E + 255) / 256;
  const int gN  = (N + 255) / 256;      // also #scan blocks (196 <= 1024)
  const int gW  = (N * 64 + 255) / 256; // one wave per node

  k_detect <<<1, 256, 0, stream>>>((const u32*)eidx, flag);
  k_norm   <<<gE, 256, 0, stream>>>(eidx, flag, src_w, dst_w, E);
  k_init   <<<gN, 256, 0, stream>>>(cnt, N);
  k_hist   <<<gE, 256, 0, stream>>>(dst_w, cnt, E);
  k_scan1  <<<gN, 256, 0, stream>>>(cnt, rp, bsum, N);
  k_scan2  <<<1, 1024, 0, stream>>>(bsum, gN);
  k_scan3  <<<gN, 256, 0, stream>>>(rp, cur, bsum, cnt, dinv_o, N, E);
  k_scatter<<<gE, 256, 0, stream>>>(src_w, dst_w, escore, cur, col, wsrt, E);
  k_deg    <<<gN, 256, 0, stream>>>(rp, wsrt, dinv_s, N);

  // agg_sx = A_score x -> B1 ; agg_ox = A_ones x -> B2
  k_agg_dual<<<gW, 256, 0, stream>>>(x, rp, col, wsrt, dinv_s, dinv_o, B1, B2, N);
  // y=0: enc_t = relu(B1@W_enc+b_enc) -> B3 ; y=1: prior = relu(B2@W_pr+b_pr)+temb -> B5
  k_gemm_act2<<<dim3(gG,2), 256, 0, stream>>>(B1, W_enc, b_enc, B2, W_pr, b_pr,
                                              temb, t_ptr, B3, B5, N);
  // agg_oe = A_ones enc_t -> B2
  k_agg_one<<<gW, 256, 0, stream>>>(B3, rp, col, dinv_o, B2, N);
  // pm = B5@W_pm + b_pm -> B3 ; ps = sigmoid(B5@W_ps + b_ps) -> B4
  k_gemm_dual<<<gG, 256, 0, stream>>>(B5, W_pm, b_pm, W_ps, b_ps, B3, B4, N);
  // em/es + conf_z + kl partials
  k_gemm_final<<<gG, 256, 0, stream>>>(B2, W_mu, b_mu, W_std, b_std, B3, B4, conf, pblk, N);
  k_finish<<<1, 256, 0, stream>>>(pblk, gG, (float*)d_out, N);
}